// Round 1
// baseline (412.090 us; speedup 1.0000x reference)
//
#include <hip/hip_runtime.h>

#define EMBED 4096
#define NHEADS 32
#define HDIM 128
#define MAXLEN 4096
#define BATCH 8

// out[m][n] = sum_k X[m][k]*W[n][k] + bias[n]  for m in [0,8)
// Block handles nWaves*RPW consecutive rows n starting at n0.
// xs: LDS buffer of 8*2048 floats (64 KB); x staged in two column-halves.
template<int RPW>
__device__ __forceinline__ void gemm8_block(const float* __restrict__ X,
                                            const float* __restrict__ W,
                                            const float* __restrict__ bias,
                                            float* __restrict__ out,
                                            int n0, float* xs)
{
    const int tid  = threadIdx.x;
    const int wave = tid >> 6, lane = tid & 63;
    const int n    = n0 + wave * RPW;

    float acc[RPW][8];
    #pragma unroll
    for (int j = 0; j < RPW; ++j)
        #pragma unroll
        for (int m = 0; m < 8; ++m) acc[j][m] = 0.f;

    for (int ph = 0; ph < 2; ++ph) {
        __syncthreads();   // protect previous phase's xs reads
        // stage X[:, ph*2048 : ph*2048+2048] into xs[8][2048]
        for (int i = tid; i < 8 * 2048 / 4; i += (int)blockDim.x) {
            int mm = i >> 9;        // /512 float4 per row
            int cc = i & 511;
            ((float4*)xs)[i] = ((const float4*)(X + mm * EMBED + ph * 2048))[cc];
        }
        __syncthreads();

        const float* wbase = W + (size_t)n * EMBED + ph * 2048;
        #pragma unroll 1
        for (int i = 0; i < 8; ++i) {
            int c = i * 256 + lane * 4;
            float4 wv[RPW];
            #pragma unroll
            for (int j = 0; j < RPW; ++j)
                wv[j] = *(const float4*)(wbase + (size_t)j * EMBED + c);
            #pragma unroll
            for (int m = 0; m < 8; ++m) {
                float4 xv = *(const float4*)(xs + m * 2048 + c);
                #pragma unroll
                for (int j = 0; j < RPW; ++j) {
                    acc[j][m] += xv.x * wv[j].x + xv.y * wv[j].y
                               + xv.z * wv[j].z + xv.w * wv[j].w;
                }
            }
        }
    }

    // cross-lane reduction: each (j,m) summed over 64 lanes
    #pragma unroll
    for (int j = 0; j < RPW; ++j)
        #pragma unroll
        for (int m = 0; m < 8; ++m) {
            float v = acc[j][m];
            #pragma unroll
            for (int off = 32; off > 0; off >>= 1) v += __shfl_xor(v, off, 64);
            if (lane == 0) out[m * EMBED + n + j] = v + bias[n + j];
        }
}

__global__ __launch_bounds__(512)
void qkv_kernel(const float* __restrict__ x,
                const float* __restrict__ Wq, const float* __restrict__ bq,
                const float* __restrict__ Wk, const float* __restrict__ bk,
                const float* __restrict__ Wv, const float* __restrict__ bv,
                float* __restrict__ qkv /* [3][8][4096] */)
{
    __shared__ float xs[8 * 2048];
    int bid  = blockIdx.x;
    int proj = bid >> 7;                 // 0:q 1:k 2:v (128 blocks each)
    int n0   = (bid & 127) * 32;         // 8 waves * 4 rows
    const float* W = proj == 0 ? Wq : (proj == 1 ? Wk : Wv);
    const float* b = proj == 0 ? bq : (proj == 1 ? bk : bv);
    float* out = qkv + (size_t)proj * (BATCH * EMBED);
    gemm8_block<4>(x, W, b, out, n0, xs);
}

__global__ __launch_bounds__(512)
void out_kernel(const float* __restrict__ attn,
                const float* __restrict__ Wo, const float* __restrict__ bo,
                float* __restrict__ out)
{
    __shared__ float xs[8 * 2048];
    gemm8_block<2>(attn, Wo, bo, out, blockIdx.x * 16, xs);  // 8 waves * 2 rows
}

__global__ __launch_bounds__(512)
void attn_kernel(const float* __restrict__ qkv,
                 const float* __restrict__ kc, const float* __restrict__ vc,
                 const int* __restrict__ clp, float* __restrict__ attn)
{
    __shared__ float sc[MAXLEN];        // 16 KB scores
    __shared__ float accw[8 * HDIM];    // 4 KB per-wave PV partials
    __shared__ float red[8];

    const int cl = *clp;
    const int T  = cl + 1;
    const int bh = blockIdx.x;
    const int b  = bh >> 5;             // /32
    const int h  = bh & 31;
    const int tid = threadIdx.x, w = tid >> 6, lane = tid & 63;

    const float* q    = qkv + (size_t)b * EMBED + h * HDIM;
    const float* knew = qkv + (size_t)BATCH * EMBED     + (size_t)b * EMBED + h * HDIM;
    const float* vnew = qkv + (size_t)2 * BATCH * EMBED + (size_t)b * EMBED + h * HDIM;
    const float* K = kc + (size_t)bh * MAXLEN * HDIM;
    const float* V = vc + (size_t)bh * MAXLEN * HDIM;

    const float scale = 0.08838834764831845f;   // 1/sqrt(128)
    float2 q2 = *(const float2*)(q + lane * 2);
    q2.x *= scale; q2.y *= scale;

    // ---- pass 1: scores = q.K^T * scale, track wave max ----
    float lmax = -3.0e38f;
    for (int t0 = w; t0 < T; t0 += 32) {
        float2 kv[4];
        #pragma unroll
        for (int u = 0; u < 4; ++u) {
            int t = t0 + u * 8;
            if (t < T) {
                const float* p = (t == cl) ? knew : (K + (size_t)t * HDIM);
                kv[u] = *(const float2*)(p + lane * 2);
            }
        }
        #pragma unroll
        for (int u = 0; u < 4; ++u) {
            int t = t0 + u * 8;
            if (t < T) {
                float s = q2.x * kv[u].x + q2.y * kv[u].y;
                #pragma unroll
                for (int off = 32; off > 0; off >>= 1) s += __shfl_xor(s, off, 64);
                if (lane == 0) sc[t] = s;
                lmax = fmaxf(lmax, s);
            }
        }
    }
    if (lane == 0) red[w] = lmax;
    __syncthreads();
    float gmax = red[0];
    #pragma unroll
    for (int i = 1; i < 8; ++i) gmax = fmaxf(gmax, red[i]);

    // ---- exp + sum ----
    float lsum = 0.f;
    for (int i = tid; i < T; i += 512) {
        float e = __expf(sc[i] - gmax);
        sc[i] = e;
        lsum += e;
    }
    #pragma unroll
    for (int off = 32; off > 0; off >>= 1) lsum += __shfl_xor(lsum, off, 64);
    __syncthreads();                     // exp writes done; red free to reuse
    if (lane == 0) red[w] = lsum;
    __syncthreads();
    float gsum = 0.f;
    #pragma unroll
    for (int i = 0; i < 8; ++i) gsum += red[i];
    const float inv = 1.0f / gsum;

    // ---- pass 2: PV ----
    float2 acc = make_float2(0.f, 0.f);
    for (int t0 = w; t0 < T; t0 += 32) {
        float2 vv[4];
        #pragma unroll
        for (int u = 0; u < 4; ++u) {
            int t = t0 + u * 8;
            if (t < T) {
                const float* p = (t == cl) ? vnew : (V + (size_t)t * HDIM);
                vv[u] = *(const float2*)(p + lane * 2);
            }
        }
        #pragma unroll
        for (int u = 0; u < 4; ++u) {
            int t = t0 + u * 8;
            if (t < T) {
                float pr = sc[t];
                acc.x += pr * vv[u].x;
                acc.y += pr * vv[u].y;
            }
        }
    }
    accw[w * HDIM + lane * 2]     = acc.x;
    accw[w * HDIM + lane * 2 + 1] = acc.y;
    __syncthreads();
    if (tid < HDIM) {
        float s = 0.f;
        #pragma unroll
        for (int ww = 0; ww < 8; ++ww) s += accw[ww * HDIM + tid];
        attn[(size_t)bh * HDIM + tid] = s * inv;
    }
}

extern "C" void kernel_launch(void* const* d_in, const int* in_sizes, int n_in,
                              void* d_out, int out_size, void* d_ws, size_t ws_size,
                              hipStream_t stream) {
    const float* x  = (const float*)d_in[0];
    const float* kc = (const float*)d_in[1];
    const float* vc = (const float*)d_in[2];
    const float* Wq = (const float*)d_in[3];
    const float* bq = (const float*)d_in[4];
    const float* Wk = (const float*)d_in[5];
    const float* bk = (const float*)d_in[6];
    const float* Wv = (const float*)d_in[7];
    const float* bv = (const float*)d_in[8];
    const float* Wo = (const float*)d_in[9];
    const float* bo = (const float*)d_in[10];
    const int* clp  = (const int*)d_in[11];

    float* out  = (float*)d_out;
    float* qkv  = (float*)d_ws;                          // 3*8*4096 f32
    float* attn = qkv + (size_t)3 * BATCH * EMBED;       // 8*4096 f32

    hipLaunchKernelGGL(qkv_kernel, dim3(384), dim3(512), 0, stream,
                       x, Wq, bq, Wk, bk, Wv, bv, qkv);
    hipLaunchKernelGGL(attn_kernel, dim3(256), dim3(512), 0, stream,
                       qkv, kc, vc, clp, attn);
    hipLaunchKernelGGL(out_kernel, dim3(256), dim3(512), 0, stream,
                       attn, Wo, bo, out);
}

// Round 2
// 268.296 us; speedup vs baseline: 1.5360x; 1.5360x over previous
//
#include <hip/hip_runtime.h>

#define EMBED 4096
#define NHEADS 32
#define HDIM 128
#define MAXLEN 4096
#define BATCH 8
#define NSPLIT 8

// ---------------- GEMM: out[m][n] = sum_k X[m][k]*W[n][k] + bias[n], m in [0,8) ----
// 256-thread blocks (4 waves), RPW rows per wave. No LDS: x is 128 KB, L2-resident.
template<int RPW>
__device__ __forceinline__ void gemm8_body(const float* __restrict__ X,
                                           const float* __restrict__ W,
                                           const float* __restrict__ bias,
                                           float* __restrict__ out, int n)
{
    const int lane = threadIdx.x & 63;

    float acc[RPW][8];
    #pragma unroll
    for (int j = 0; j < RPW; ++j)
        #pragma unroll
        for (int m = 0; m < 8; ++m) acc[j][m] = 0.f;

    const float* wb = W + (size_t)n * EMBED;

    #pragma unroll 1
    for (int i = 0; i < 16; ++i) {
        int c = i * 256 + lane * 4;
        float4 wv[RPW];
        #pragma unroll
        for (int j = 0; j < RPW; ++j)
            wv[j] = *(const float4*)(wb + (size_t)j * EMBED + c);
        #pragma unroll
        for (int m = 0; m < 8; ++m) {
            float4 xv = *(const float4*)(X + (size_t)m * EMBED + c);
            #pragma unroll
            for (int j = 0; j < RPW; ++j) {
                acc[j][m] += xv.x * wv[j].x + xv.y * wv[j].y
                           + xv.z * wv[j].z + xv.w * wv[j].w;
            }
        }
    }

    #pragma unroll
    for (int j = 0; j < RPW; ++j)
        #pragma unroll
        for (int m = 0; m < 8; ++m) {
            float v = acc[j][m];
            #pragma unroll
            for (int off = 32; off > 0; off >>= 1) v += __shfl_xor(v, off, 64);
            if (lane == 0) out[(size_t)m * EMBED + n + j] = v + bias[n + j];
        }
}

__global__ __launch_bounds__(256)
void qkv_kernel(const float* __restrict__ x,
                const float* __restrict__ Wq, const float* __restrict__ bq,
                const float* __restrict__ Wk, const float* __restrict__ bk,
                const float* __restrict__ Wv, const float* __restrict__ bv,
                float* __restrict__ qkv /* [3][8][4096] */)
{
    const int wave = threadIdx.x >> 6;
    int ng = blockIdx.x * 16 + wave * 4;     // global row among 3*4096
    int proj = ng >> 12;
    int n = ng & 4095;
    const float* W = proj == 0 ? Wq : (proj == 1 ? Wk : Wv);
    const float* b = proj == 0 ? bq : (proj == 1 ? bk : bv);
    float* out = qkv + (size_t)proj * (BATCH * EMBED);
    gemm8_body<4>(x, W, b, out, n);
}

__global__ __launch_bounds__(256)
void out_kernel(const float* __restrict__ attn,
                const float* __restrict__ Wo, const float* __restrict__ bo,
                float* __restrict__ out)
{
    const int wave = threadIdx.x >> 6;
    int n = blockIdx.x * 8 + wave * 2;
    gemm8_body<2>(attn, Wo, bo, out, n);
}

// ---------------- flash-decode attention: partial per (bh, split) ----------------
__global__ __launch_bounds__(256)
void attn_partial(const float* __restrict__ qkv,
                  const float* __restrict__ kc, const float* __restrict__ vc,
                  const int* __restrict__ clp,
                  float* __restrict__ part_acc,   // [256][NSPLIT][128]
                  float* __restrict__ part_ms)    // [256][NSPLIT][2]
{
    __shared__ float sc[512];
    __shared__ float accw[4 * HDIM];
    __shared__ float redm[4], reds[4];

    const int cl = *clp;
    const int T  = cl + 1;
    const int CH = (T + NSPLIT - 1) / NSPLIT;

    const int bh = blockIdx.x & 255;
    const int sp = blockIdx.x >> 8;
    const int b  = bh >> 5;
    const int h  = bh & 31;
    const int tid = threadIdx.x, w = tid >> 6, lane = tid & 63;
    const int half = lane >> 5, col4 = lane & 31;

    const int tstart = sp * CH;
    const int tend   = min(T, tstart + CH);
    const int len    = tend - tstart;

    const float* q    = qkv + (size_t)b * EMBED + h * HDIM;
    const float* knew = qkv + (size_t)BATCH * EMBED     + (size_t)b * EMBED + h * HDIM;
    const float* vnew = qkv + (size_t)2 * BATCH * EMBED + (size_t)b * EMBED + h * HDIM;
    const float* K = kc + (size_t)bh * MAXLEN * HDIM;
    const float* V = vc + (size_t)bh * MAXLEN * HDIM;

    const float scale = 0.08838834764831845f;   // 1/sqrt(128)
    float4 qv = *(const float4*)(q + col4 * 4);
    qv.x *= scale; qv.y *= scale; qv.z *= scale; qv.w *= scale;

    // ---- pass 1: scores ----
    float lmax = -3.0e38f;
    for (int base = tstart + w * 8; base < tend; base += 32) {
        float4 kv[4];
        #pragma unroll
        for (int u = 0; u < 4; ++u) {
            int t = base + u * 2 + half;
            if (t < tend) {
                const float* p = (t == cl) ? knew : (K + (size_t)t * HDIM);
                kv[u] = *(const float4*)(p + col4 * 4);
            } else {
                kv[u] = make_float4(0.f, 0.f, 0.f, 0.f);
            }
        }
        #pragma unroll
        for (int u = 0; u < 4; ++u) {
            int t = base + u * 2 + half;
            float s = qv.x * kv[u].x + qv.y * kv[u].y + qv.z * kv[u].z + qv.w * kv[u].w;
            #pragma unroll
            for (int off = 16; off > 0; off >>= 1) s += __shfl_xor(s, off, 64);
            if (t < tend) {
                if (col4 == 0) sc[t - tstart] = s;
                lmax = fmaxf(lmax, s);
            }
        }
    }
    lmax = fmaxf(lmax, __shfl_xor(lmax, 32, 64));
    if (lane == 0) redm[w] = lmax;
    __syncthreads();
    float gmax = fmaxf(fmaxf(redm[0], redm[1]), fmaxf(redm[2], redm[3]));

    // ---- exp + sum over chunk ----
    float lsum = 0.f;
    for (int i = tid; i < len; i += 256) {
        float e = __expf(sc[i] - gmax);
        sc[i] = e;
        lsum += e;
    }
    #pragma unroll
    for (int off = 32; off > 0; off >>= 1) lsum += __shfl_xor(lsum, off, 64);
    if (lane == 0) reds[w] = lsum;
    __syncthreads();            // covers sc writes + reds
    float csum = reds[0] + reds[1] + reds[2] + reds[3];

    // ---- pass 2: PV ----
    float4 acc = make_float4(0.f, 0.f, 0.f, 0.f);
    for (int base = tstart + w * 8; base < tend; base += 32) {
        float4 vv[4];
        float  pr[4];
        #pragma unroll
        for (int u = 0; u < 4; ++u) {
            int t = base + u * 2 + half;
            if (t < tend) {
                const float* p = (t == cl) ? vnew : (V + (size_t)t * HDIM);
                vv[u] = *(const float4*)(p + col4 * 4);
                pr[u] = sc[t - tstart];
            } else {
                vv[u] = make_float4(0.f, 0.f, 0.f, 0.f);
                pr[u] = 0.f;
            }
        }
        #pragma unroll
        for (int u = 0; u < 4; ++u) {
            acc.x += pr[u] * vv[u].x;
            acc.y += pr[u] * vv[u].y;
            acc.z += pr[u] * vv[u].z;
            acc.w += pr[u] * vv[u].w;
        }
    }
    acc.x += __shfl_xor(acc.x, 32, 64);
    acc.y += __shfl_xor(acc.y, 32, 64);
    acc.z += __shfl_xor(acc.z, 32, 64);
    acc.w += __shfl_xor(acc.w, 32, 64);
    if (half == 0) *(float4*)(accw + w * HDIM + col4 * 4) = acc;
    __syncthreads();

    const size_t pidx = (size_t)bh * NSPLIT + sp;
    if (tid < HDIM) {
        float s = accw[tid] + accw[HDIM + tid] + accw[2 * HDIM + tid] + accw[3 * HDIM + tid];
        part_acc[pidx * HDIM + tid] = s;
    }
    if (tid == 0) {
        part_ms[pidx * 2]     = gmax;
        part_ms[pidx * 2 + 1] = csum;
    }
}

__global__ __launch_bounds__(128)
void combine_kernel(const float* __restrict__ part_acc,
                    const float* __restrict__ part_ms,
                    float* __restrict__ attn)
{
    const int bh = blockIdx.x;
    const int d  = threadIdx.x;

    float m[NSPLIT], s[NSPLIT];
    float gmax = -3.0e38f;
    #pragma unroll
    for (int sp = 0; sp < NSPLIT; ++sp) {
        m[sp] = part_ms[((size_t)bh * NSPLIT + sp) * 2];
        s[sp] = part_ms[((size_t)bh * NSPLIT + sp) * 2 + 1];
        gmax  = fmaxf(gmax, m[sp]);
    }
    float total = 0.f, o = 0.f;
    #pragma unroll
    for (int sp = 0; sp < NSPLIT; ++sp) {
        float wgt = __expf(m[sp] - gmax);
        total += s[sp] * wgt;
        o += part_acc[((size_t)bh * NSPLIT + sp) * HDIM + d] * wgt;
    }
    attn[(size_t)bh * HDIM + d] = o / total;
}

extern "C" void kernel_launch(void* const* d_in, const int* in_sizes, int n_in,
                              void* d_out, int out_size, void* d_ws, size_t ws_size,
                              hipStream_t stream) {
    const float* x  = (const float*)d_in[0];
    const float* kc = (const float*)d_in[1];
    const float* vc = (const float*)d_in[2];
    const float* Wq = (const float*)d_in[3];
    const float* bq = (const float*)d_in[4];
    const float* Wk = (const float*)d_in[5];
    const float* bk = (const float*)d_in[6];
    const float* Wv = (const float*)d_in[7];
    const float* bv = (const float*)d_in[8];
    const float* Wo = (const float*)d_in[9];
    const float* bo = (const float*)d_in[10];
    const int* clp  = (const int*)d_in[11];

    float* out      = (float*)d_out;
    float* qkv      = (float*)d_ws;                               // 3*8*4096
    float* attn     = qkv + (size_t)3 * BATCH * EMBED;            // 8*4096
    float* part_acc = attn + (size_t)BATCH * EMBED;               // 256*8*128
    float* part_ms  = part_acc + (size_t)256 * NSPLIT * HDIM;     // 256*8*2

    hipLaunchKernelGGL(qkv_kernel, dim3(768), dim3(256), 0, stream,
                       x, Wq, bq, Wk, bk, Wv, bv, qkv);
    hipLaunchKernelGGL(attn_partial, dim3(256 * NSPLIT), dim3(256), 0, stream,
                       qkv, kc, vc, clp, part_acc, part_ms);
    hipLaunchKernelGGL(combine_kernel, dim3(256), dim3(128), 0, stream,
                       part_acc, part_ms, attn);
    hipLaunchKernelGGL(out_kernel, dim3(512), dim3(256), 0, stream,
                       attn, Wo, bo, out);
}